// Round 1
// baseline (561.569 us; speedup 1.0000x reference)
//
#include <hip/hip_runtime.h>
#include <math.h>

#define Lseq 256
#define Bn   32
#define Cn   64
#define WIN  22   // decay window: exp(-22^2/8) = 5e-27, far below fp32 noise

__global__ void zero_loss_kernel(float* p) { *p = 0.0f; }

// One block per (l,b). Five 64x64 matrices, each read exactly once with
// coalesced float4 loads ALL issued up front (no barrier between passes):
// column-einsum partials and row-einsum partials accumulate in registers,
// reduced once at the end (1 shfl tree + 1 LDS staging round).
__global__ __launch_bounds__(256, 4) void tf_criterion_kernel(
    const float* __restrict__ f,   const float* __restrict__ s,
    const float* __restrict__ fs,  const float* __restrict__ ff,
    const float* __restrict__ ss,  const float* __restrict__ fs_t,
    const float* __restrict__ sf_t,
    const int* __restrict__ f_labels, const int* __restrict__ s_labels,
    float* __restrict__ out)
{
  __shared__ __align__(16) float stageNF[1024];   // 4 KB col-partial staging (nf)
  __shared__ __align__(16) float stageNS[1024];   // 4 KB col-partial staging (ns)
  __shared__ __align__(16) float f_mp[64], f_mf[64], s_mp[64], s_mf[64];
  __shared__ __align__(16) float prev_f[64], prev_s[64];
  __shared__ float nfR[64], nsR[64];              // row-einsum sums
  __shared__ float nfv[64], nsv[64];              // final next_f / next_s
  __shared__ float lp[4];

  const int tid = threadIdx.x;
  const int lb  = blockIdx.x;              // lb = l*B + b
  const int l   = lb >> 5;
  const int b   = lb & 31;
  const int cb  = tid & 15;                // column block (4 cols)
  const int m   = tid >> 4;                // row-chunk id 0..15

  // ---- issue ALL 20 matrix fragment loads first: max memory-level parallelism
  const size_t mo = (size_t)lb * 4096;
  const float4* M_ff = (const float4*)(ff   + mo);
  const float4* M_ss = (const float4*)(ss   + mo);
  const float4* M_sf = (const float4*)(sf_t + mo);
  const float4* M_ft = (const float4*)(fs_t + mo);
  const float4* M_fs = (const float4*)(fs   + mo);
  float4 v_ff[4], v_ss[4], v_sf[4], v_ft[4], v_fs[4];
#pragma unroll
  for (int k = 0; k < 4; ++k) v_ff[k] = M_ff[tid + 256*k];
#pragma unroll
  for (int k = 0; k < 4; ++k) v_ss[k] = M_ss[tid + 256*k];
#pragma unroll
  for (int k = 0; k < 4; ++k) v_sf[k] = M_sf[tid + 256*k];
#pragma unroll
  for (int k = 0; k < 4; ++k) v_ft[k] = M_ft[tid + 256*k];
#pragma unroll
  for (int k = 0; k < 4; ++k) v_fs[k] = M_fs[tid + 256*k];

  // ---- phase 0: windowed-decay message vectors; 4x64-thread groups
  // (past/future x f/s); fixed trip count -> weights constant-folded, no expf.
  {
    const int grp = tid >> 6;              // 0:f-past(+pv) 1:f-fut 2:s-past(+pv) 3:s-fut
    const int c   = tid & 63;
    const float* src = (grp & 2) ? s : f;
    float acc = 0.f;
    if ((grp & 1) == 0) {
#pragma unroll
      for (int j = 1; j <= WIN; ++j) {
        int i = l - j;
        bool valid = (i >= 0);
        float w = valid ? expf(-0.125f * (float)(j * j)) : 0.f;  // compile-time
        int idx = valid ? i : 0;
        acc += w * src[((size_t)idx * Bn + b) * Cn + c];
      }
      acc *= 1.0f / (float)((l > 1) ? l : 1);
      float pv = src[((size_t)l * Bn + b) * Cn + c];
      if (grp == 0) { f_mp[c] = acc; prev_f[c] = pv; }
      else          { s_mp[c] = acc; prev_s[c] = pv; }
    } else {
#pragma unroll
      for (int j = 1; j <= WIN; ++j) {
        int i = l + j;
        bool valid = (i <= Lseq - 1);
        float w = valid ? expf(-0.125f * (float)(j * j)) : 0.f;  // compile-time
        int idx = valid ? i : 0;
        acc += w * src[((size_t)idx * Bn + b) * Cn + c];
      }
      acc *= 1.0f / (float)((Lseq - 1 - l > 1) ? (Lseq - 1 - l) : 1);
      if (grp == 1) f_mf[c] = acc; else s_mf[c] = acc;
    }
  }
  __syncthreads();

  // ---- all five passes, barrier-free, register accumulation
  // col-einsums: ff(f_mp)->nf, sf_t(s_mp)->nf, ss(s_mp)->ns, fs_t(f_mp)->ns, fs(prev_f)->ns
  // row-einsums: ff(f_mf)->nf, fs_t(s_mf)->nf, fs(prev_s)->nf, ss(s_mf)->ns, sf_t(f_mf)->ns
  float accNF[4] = {0,0,0,0}, accNS[4] = {0,0,0,0};
  float rowNF[4] = {0,0,0,0}, rowNS[4] = {0,0,0,0};
  const float4 c_fmf = ((const float4*)f_mf)[cb];
  const float4 c_smf = ((const float4*)s_mf)[cb];
  const float4 c_ps  = ((const float4*)prev_s)[cb];

#pragma unroll
  for (int k = 0; k < 4; ++k) {
    const int r = m + 16*k;
    const float vfp = f_mp[r], vsp = s_mp[r], vpf = prev_f[r];
    { float4 v = v_ff[k];   // ff
      accNF[0]+=vfp*v.x; accNF[1]+=vfp*v.y; accNF[2]+=vfp*v.z; accNF[3]+=vfp*v.w;
      rowNF[k]+= v.x*c_fmf.x + v.y*c_fmf.y + v.z*c_fmf.z + v.w*c_fmf.w; }
    { float4 v = v_ss[k];   // ss
      accNS[0]+=vsp*v.x; accNS[1]+=vsp*v.y; accNS[2]+=vsp*v.z; accNS[3]+=vsp*v.w;
      rowNS[k]+= v.x*c_smf.x + v.y*c_smf.y + v.z*c_smf.z + v.w*c_smf.w; }
    { float4 v = v_sf[k];   // sf_t [s,f]
      accNF[0]+=vsp*v.x; accNF[1]+=vsp*v.y; accNF[2]+=vsp*v.z; accNF[3]+=vsp*v.w;
      rowNS[k]+= v.x*c_fmf.x + v.y*c_fmf.y + v.z*c_fmf.z + v.w*c_fmf.w; }
    { float4 v = v_ft[k];   // fs_t [f,s]
      accNS[0]+=vfp*v.x; accNS[1]+=vfp*v.y; accNS[2]+=vfp*v.z; accNS[3]+=vfp*v.w;
      rowNF[k]+= v.x*c_smf.x + v.y*c_smf.y + v.z*c_smf.z + v.w*c_smf.w; }
    { float4 v = v_fs[k];   // fs [f,s]
      accNS[0]+=vpf*v.x; accNS[1]+=vpf*v.y; accNS[2]+=vpf*v.z; accNS[3]+=vpf*v.w;
      rowNF[k]+= v.x*c_ps.x + v.y*c_ps.y + v.z*c_ps.z + v.w*c_ps.w; }
  }

  // ---- single deferred reduction
  // rows: reduce over the 16 lanes (cb) sharing each row set
#pragma unroll
  for (int k = 0; k < 4; ++k) {
#pragma unroll
    for (int off = 8; off >= 1; off >>= 1) {
      rowNF[k] += __shfl_xor(rowNF[k], off, 64);
      rowNS[k] += __shfl_xor(rowNS[k], off, 64);
    }
  }
  if (cb == 0) {
#pragma unroll
    for (int k = 0; k < 4; ++k) { nfR[m+16*k] = rowNF[k]; nsR[m+16*k] = rowNS[k]; }
  }
  // cols: stage partials (conflict-free float4 writes), one barrier, tree in smem
  reinterpret_cast<float4*>(stageNF)[m*16 + cb] =
      make_float4(accNF[0], accNF[1], accNF[2], accNF[3]);
  reinterpret_cast<float4*>(stageNS)[m*16 + cb] =
      make_float4(accNS[0], accNS[1], accNS[2], accNS[3]);
  __syncthreads();

  if (tid < 128) {
    const int c = tid & 63;
    const float* stg = (tid < 64) ? stageNF : stageNS;
    float acc = 0.f;
#pragma unroll
    for (int mm = 0; mm < 16; ++mm) acc += stg[mm*64 + c];
    if (tid < 64) nfv[c] = prev_f[c] + 0.5f * (acc + nfR[c]);
    else          nsv[c] = prev_s[c] + 0.5f * (acc + nsR[c]);
  }
  __syncthreads();

  // ---- epilogue: softmax outputs + 4 cross-entropy row contributions
  const int w = tid >> 6;   // wave id: 0=f, 1=s, 2=next_f, 3=next_s
  const int c = tid & 63;
  float x;
  if      (w == 0) x = prev_f[c];
  else if (w == 1) x = prev_s[c];
  else if (w == 2) x = nfv[c];
  else             x = nsv[c];

  float mx = x;
#pragma unroll
  for (int off = 32; off >= 1; off >>= 1)
    mx = fmaxf(mx, __shfl_xor(mx, off, 64));
  float e  = expf(x - mx);
  float sm = e;
#pragma unroll
  for (int off = 32; off >= 1; off >>= 1)
    sm += __shfl_xor(sm, off, 64);

  if      (w == 2) out[(size_t)lb * 64 + c]          = e / sm;
  else if (w == 3) out[524288 + (size_t)lb * 64 + c] = e / sm;

  float lse = logf(sm) + mx;
  int lab = (w & 1) ? s_labels[lb] : f_labels[lb];
  if (c == lab) lp[w] = lse - x;
  __syncthreads();
  if (tid == 0)
    atomicAdd(out + 1048576, (lp[0] + lp[1] + lp[2] + lp[3]) * (1.0f / 8192.0f));
}

extern "C" void kernel_launch(void* const* d_in, const int* in_sizes, int n_in,
                              void* d_out, int out_size, void* d_ws, size_t ws_size,
                              hipStream_t stream) {
  const float* f     = (const float*)d_in[0];
  const float* s     = (const float*)d_in[1];
  const float* fs    = (const float*)d_in[2];
  const float* ff    = (const float*)d_in[3];
  const float* ss    = (const float*)d_in[4];
  const float* fs_t  = (const float*)d_in[5];
  const float* sf_t  = (const float*)d_in[6];
  const int*   f_lab = (const int*)d_in[7];
  const int*   s_lab = (const int*)d_in[8];
  float* out = (float*)d_out;

  zero_loss_kernel<<<1, 1, 0, stream>>>(out + 1048576);
  tf_criterion_kernel<<<Lseq * Bn, 256, 0, stream>>>(
      f, s, fs, ff, ss, fs_t, sf_t, f_lab, s_lab, out);
}

// Round 3
// 560.793 us; speedup vs baseline: 1.0014x; 1.0014x over previous
//
#include <hip/hip_runtime.h>
#include <math.h>

#define Lseq 256
#define Bn   32
#define Cn   64
#define WIN  22   // decay window: exp(-22^2/8) = 5e-27, far below fp32 noise

__global__ void zero_loss_kernel(float* p) { *p = 0.0f; }

// Precompute gaussian-window messages into workspace:
//   fmp[l,b,c] = (1/max(l,1))       * sum_{j=1..WIN, l-j>=0}  w_j f[l-j,b,c]
//   fmf[l,b,c] = (1/max(L-1-l,1))   * sum_{j=1..WIN, l+j<L}   w_j f[l+j,b,c]
// f,s are 2 MB each -> L2-resident; fully unrolled independent loads.
__global__ __launch_bounds__(256) void msg_kernel(
    const float* __restrict__ f, const float* __restrict__ s,
    float* __restrict__ fmp, float* __restrict__ fmf,
    float* __restrict__ smp, float* __restrict__ smf)
{
  const int bid = blockIdx.x;
  const int l   = bid >> 3;                       // 8 blocks per l
  const int p   = ((bid & 7) << 8) + threadIdx.x; // pair index (b*64+c), 0..2047
  const size_t base = (size_t)l * 2048 + p;

  float fp = 0.f, fu = 0.f, sp = 0.f, su = 0.f;
#pragma unroll
  for (int j = 1; j <= WIN; ++j) {
    const float w = expf(-0.125f * (float)(j * j));  // constant-folded
    const int ip = l - j;                            // block-uniform predicate
    if (ip >= 0) {
      fp += w * f[(size_t)ip * 2048 + p];
      sp += w * s[(size_t)ip * 2048 + p];
    }
    const int iq = l + j;
    if (iq < Lseq) {
      fu += w * f[(size_t)iq * 2048 + p];
      su += w * s[(size_t)iq * 2048 + p];
    }
  }
  const float rp = 1.0f / (float)((l > 1) ? l : 1);
  const float rf = 1.0f / (float)((Lseq - 1 - l > 1) ? (Lseq - 1 - l) : 1);
  fmp[base] = fp * rp;
  fmf[base] = fu * rf;
  smp[base] = sp * rp;
  smf[base] = su * rf;
}

// Process one 64x64 matrix for one (l,b):
//   einsum A (cols): outA[c] += wA * sum_r vrow[r] * M[r][c]
//   einsum B (rows): outB[r] += wB * sum_c M[r][c] * vcol[c]
// Reads M exactly once with coalesced float4 loads.
__device__ __forceinline__ void mat_pass(
    const float4* __restrict__ M4,
    const float* __restrict__ vrow, const float* __restrict__ vcol,
    float* outA, float* outB, float wA, float wB,
    float* stage /*1024 floats, float4-aligned*/, int tid)
{
  const int cb = tid & 15;   // column block (4 cols)
  const int m  = tid >> 4;   // row-chunk id 0..15
  const float vc0 = vcol[4*cb+0], vc1 = vcol[4*cb+1];
  const float vc2 = vcol[4*cb+2], vc3 = vcol[4*cb+3];
  float pA0 = 0.f, pA1 = 0.f, pA2 = 0.f, pA3 = 0.f;
  float pB[4];
#pragma unroll
  for (int k = 0; k < 4; ++k) {
    float4 v = M4[tid + 256*k];       // row r = m + 16k, cols 4cb..4cb+3
    float vr = vrow[m + 16*k];
    pA0 += vr * v.x; pA1 += vr * v.y; pA2 += vr * v.z; pA3 += vr * v.w;
    pB[k] = v.x*vc0 + v.y*vc1 + v.z*vc2 + v.w*vc3;
  }
  // stage column partials (float4 -> conflict-free ds_write_b128)
  reinterpret_cast<float4*>(stage)[m*16 + cb] = make_float4(pA0, pA1, pA2, pA3);
  // reduce row partials across the 16 lanes sharing this row set
#pragma unroll
  for (int k = 0; k < 4; ++k) {
#pragma unroll
    for (int off = 8; off >= 1; off >>= 1)
      pB[k] += __shfl_xor(pB[k], off, 64);
  }
  if (cb == 0) {
#pragma unroll
    for (int k = 0; k < 4; ++k)
      outB[m + 16*k] += wB * pB[k];   // each row has exactly one writer
  }
  __syncthreads();
  if (tid < 64) {
    float acc = 0.f;
#pragma unroll
    for (int mm = 0; mm < 16; ++mm) acc += stage[mm*64 + tid];
    outA[tid] += wA * acc;
  }
  __syncthreads();
}

__global__ __launch_bounds__(256) void tf_criterion_kernel(
    const float* __restrict__ f,   const float* __restrict__ s,
    const float* __restrict__ fs,  const float* __restrict__ ff,
    const float* __restrict__ ss,  const float* __restrict__ fs_t,
    const float* __restrict__ sf_t,
    const float* __restrict__ fmp_g, const float* __restrict__ fmf_g,
    const float* __restrict__ smp_g, const float* __restrict__ smf_g,
    const int* __restrict__ f_labels, const int* __restrict__ s_labels,
    float* __restrict__ out, int use_msgs)
{
  __shared__ float4 stage4[256];           // 4 KB staging for column reductions
  __shared__ float f_mp[64], f_mf[64], s_mp[64], s_mf[64];
  __shared__ float prev_f[64], prev_s[64];
  __shared__ float nf[64], ns[64];         // accumulated deltas for next_f/next_s
  __shared__ float lp[4];

  const int tid = threadIdx.x;
  const int lb  = blockIdx.x;              // lb = l*B + b
  const int l   = lb >> 5;
  const int b   = lb & 31;

  // ---- phase 0: message vectors + prev rows ----
  if (use_msgs) {
    if (tid < 128) {
      const int which = tid >> 6;          // 0: f, 1: s
      const int c     = tid & 63;
      const size_t base = (size_t)lb * 64 + c;   // == (l*B+b)*64+c
      if (which == 0) {
        f_mp[c] = fmp_g[base]; f_mf[c] = fmf_g[base]; prev_f[c] = f[base];
      } else {
        s_mp[c] = smp_g[base]; s_mf[c] = smf_g[base]; prev_s[c] = s[base];
      }
    } else if (tid < 192) {
      nf[tid - 128] = 0.f;
    } else {
      ns[tid - 192] = 0.f;
    }
  } else {
    // fallback: compute windowed decay matvec inline (known-good round-0 path)
    if (tid < 128) {
      const int which = tid >> 6;          // 0: f, 1: s
      const int c     = tid & 63;
      const float* src = which ? s : f;
      float mp = 0.f, mf = 0.f, pv = 0.f;
      int i0 = l - WIN; if (i0 < 0) i0 = 0;
      int i1 = l + WIN; if (i1 > Lseq - 1) i1 = Lseq - 1;
      for (int i = i0; i <= i1; ++i) {
        float x = src[((size_t)i * Bn + b) * Cn + c];
        int d = l - i;
        if (d == 0) { pv = x; continue; }
        float w = expf(-0.125f * (float)(d * d));
        if (d > 0) mp += w * x; else mf += w * x;
      }
      mp *= 1.0f / (float)((l > 1) ? l : 1);
      mf *= 1.0f / (float)((Lseq - 1 - l > 1) ? (Lseq - 1 - l) : 1);
      if (which == 0) { f_mp[c] = mp; f_mf[c] = mf; prev_f[c] = pv; }
      else            { s_mp[c] = mp; s_mf[c] = mf; prev_s[c] = pv; }
    } else if (tid < 192) {
      nf[tid - 128] = 0.f;
    } else {
      ns[tid - 192] = 0.f;
    }
  }
  __syncthreads();

  // ---- phase 1: stream the five 64x64 matrices, each read exactly once ----
  float* stage = reinterpret_cast<float*>(stage4);
  const size_t mo = (size_t)lb * 4096;
  // ff:   A: f_mp . ff -> nf (W_T)      B: ff . f_mf -> nf (W_T)
  mat_pass((const float4*)(ff   + mo), f_mp,   f_mf,   nf, nf, 0.5f, 0.5f, stage, tid);
  // ss:   A: s_mp . ss -> ns            B: ss . s_mf -> ns
  mat_pass((const float4*)(ss   + mo), s_mp,   s_mf,   ns, ns, 0.5f, 0.5f, stage, tid);
  // sf_t [s,f]: A: s_mp . M -> nf       B: M . f_mf -> ns
  mat_pass((const float4*)(sf_t + mo), s_mp,   f_mf,   nf, ns, 0.5f, 0.5f, stage, tid);
  // fs_t [f,s]: A: f_mp . M -> ns       B: M . s_mf -> nf
  mat_pass((const float4*)(fs_t + mo), f_mp,   s_mf,   ns, nf, 0.5f, 0.5f, stage, tid);
  // fs [f,s]:   A: prev_f . M -> ns (W_S)  B: M . prev_s -> nf (W_S)
  mat_pass((const float4*)(fs   + mo), prev_f, prev_s, ns, nf, 0.5f, 0.5f, stage, tid);

  // ---- epilogue: softmax outputs + 4 cross-entropy row contributions ----
  const int w = tid >> 6;   // wave id: 0=f, 1=s, 2=next_f, 3=next_s
  const int c = tid & 63;
  float x;
  if      (w == 0) x = prev_f[c];
  else if (w == 1) x = prev_s[c];
  else if (w == 2) x = prev_f[c] + nf[c];
  else             x = prev_s[c] + ns[c];

  float mx = x;
#pragma unroll
  for (int off = 32; off >= 1; off >>= 1)
    mx = fmaxf(mx, __shfl_xor(mx, off, 64));
  float e  = expf(x - mx);
  float sm = e;
#pragma unroll
  for (int off = 32; off >= 1; off >>= 1)
    sm += __shfl_xor(sm, off, 64);

  if      (w == 2) out[(size_t)lb * 64 + c]          = e / sm;
  else if (w == 3) out[524288 + (size_t)lb * 64 + c] = e / sm;

  float lse = logf(sm) + mx;
  int lab = (w & 1) ? s_labels[lb] : f_labels[lb];
  if (c == lab) lp[w] = lse - x;
  __syncthreads();
  if (tid == 0)
    atomicAdd(out + 1048576, (lp[0] + lp[1] + lp[2] + lp[3]) * (1.0f / 8192.0f));
}

extern "C" void kernel_launch(void* const* d_in, const int* in_sizes, int n_in,
                              void* d_out, int out_size, void* d_ws, size_t ws_size,
                              hipStream_t stream) {
  const float* f     = (const float*)d_in[0];
  const float* s     = (const float*)d_in[1];
  const float* fs    = (const float*)d_in[2];
  const float* ff    = (const float*)d_in[3];
  const float* ss    = (const float*)d_in[4];
  const float* fs_t  = (const float*)d_in[5];
  const float* sf_t  = (const float*)d_in[6];
  const int*   f_lab = (const int*)d_in[7];
  const int*   s_lab = (const int*)d_in[8];
  float* out = (float*)d_out;

  // workspace layout: 4 message tensors of L*B*Cn floats (2 MB each)
  const size_t msg_elems = (size_t)Lseq * Bn * Cn;
  const size_t ws_needed = 4 * msg_elems * sizeof(float);
  const int use_msgs = (d_ws != nullptr && ws_size >= ws_needed) ? 1 : 0;

  float* fmp = (float*)d_ws;
  float* fmf = fmp + msg_elems;
  float* smp = fmf + msg_elems;
  float* smf = smp + msg_elems;

  zero_loss_kernel<<<1, 1, 0, stream>>>(out + 1048576);
  if (use_msgs)
    msg_kernel<<<Lseq * 8, 256, 0, stream>>>(f, s, fmp, fmf, smp, smf);
  tf_criterion_kernel<<<Lseq * Bn, 256, 0, stream>>>(
      f, s, fs, ff, ss, fs_t, sf_t, fmp, fmf, smp, smf, f_lab, s_lab, out,
      use_msgs);
}